// Round 8
// baseline (338.959 us; speedup 1.0000x reference)
//
#include <hip/hip_runtime.h>
#include <hip/hip_bf16.h>

// Problem constants: B=4, N=1024, C=1152, H=16, hd=72
#define PB 4
#define PN 1024
#define PC 1152
#define PH 16
#define PHD 72
#define BH 64
#define QKV_COLS 3456
#define OUT_ELEMS ((size_t)PB*PN*PC)   // 4718592
#define K_DIM 1152

// Blocked f16 layouts (per (bh, 64-row chunk), 6144 halves = 12288 B):
//  q/k:  [dq(12)][row(64)][8]   element (n,d) -> (d>>3)*512 + (n&63)*8 + (d&7)
//  vt :  [kq(8)][hd(96)][8]     element (n,d) -> ((n&63)>>3)*768 + d*8 + (n&7)
// Pad-dim tricks (prep_all):
//  q[d=72] = -4.0, k[d=72] = 1.0 (own + enc)  -> QK^T MFMA emits S - 4
//    directly (fixed base-2 softmax shift; exact softmax identity).
//  vt[d=72] = 1.0                             -> PV MFMA accumulates the
//    softmax denominator l in O[4][0] of quad-2 lanes for free.
#define CHUNK_HALVES 6144
#define HEAD_HALVES (16*CHUNK_HALVES)       // 98304
#define BUF_HALVES ((size_t)BH*HEAD_HALVES) // 6291456 per buffer

typedef _Float16 half8_t __attribute__((ext_vector_type(8)));
typedef _Float16 half4_t __attribute__((ext_vector_type(4)));
typedef float float4v __attribute__((ext_vector_type(4)));

// q pre-scale: hd^-0.5 * log2(e)  (softmax computed base-2, exactly equivalent)
#define QSCALE (0.11785113019775792f * 1.4426950408889634f)

__device__ __forceinline__ void load16_lds(const _Float16* g, _Float16* l) {
    __builtin_amdgcn_global_load_lds(
        (const __attribute__((address_space(1))) void*)g,
        (__attribute__((address_space(3))) void*)l, 16, 0, 0);
}

__device__ __forceinline__ half8_t cvt8(const float* p) {
    float4 a = *(const float4*)p;
    float4 b = *(const float4*)(p + 4);
    half8_t h;
    h[0] = (_Float16)a.x; h[1] = (_Float16)a.y; h[2] = (_Float16)a.z; h[3] = (_Float16)a.w;
    h[4] = (_Float16)b.x; h[5] = (_Float16)b.y; h[6] = (_Float16)b.z; h[7] = (_Float16)b.w;
    return h;
}

// ---------------------------------------------------------------------------
// ONE prep kernel for everything that precedes the GEMMs:
//  [0,S0):    x f32->f16              [S0,S1): qkv_w      [S1,S2): proj_w
//  [S2,S3):   q pads (d=72:-4, 73..95:0)
//  [S3,S4):   k pads own+enc (d=72:1, 73..95:0)
//  [S4,S5):   vt/evt ones row d=72
//  [S5,S6):   loss slot zero (1 task)
//  [S6,S7):   enc_k -> blocked k layout (16-B stores)
//  [S7,S8):   enc_v -> blocked vt layout (lane-coalesced gather, 16-B stores)
// ---------------------------------------------------------------------------
#define S0 589824
#define S1 1087488
#define S2 1253376
#define S3 1449984
#define S4 1843200
#define S5 1859584
#define S6 1859585
#define S7 2449409
#define S8 3039233

__global__ __launch_bounds__(256) void prep_all(
    const float* __restrict__ x, const float* __restrict__ qkv_w,
    const float* __restrict__ proj_w,
    const float* __restrict__ ek, const float* __restrict__ ev,
    _Float16* __restrict__ xh, _Float16* __restrict__ qkvwh,
    _Float16* __restrict__ projwh,
    _Float16* __restrict__ qh, _Float16* __restrict__ kh, _Float16* __restrict__ ekh,
    _Float16* __restrict__ vth, _Float16* __restrict__ evth,
    float* __restrict__ loss_out)
{
    int i = blockIdx.x * 256 + threadIdx.x;
    if (i >= S8) return;

    if (i < S0) {                                   // x conversion
        ((half8_t*)xh)[i] = cvt8(x + (size_t)i * 8);
    } else if (i < S1) {                            // qkv_w conversion
        int j = i - S0;
        ((half8_t*)qkvwh)[j] = cvt8(qkv_w + (size_t)j * 8);
    } else if (i < S2) {                            // proj_w conversion
        int j = i - S1;
        ((half8_t*)projwh)[j] = cvt8(proj_w + (size_t)j * 8);
    } else if (i < S3) {                            // q pads
        int j = i - S2;
        int chunk = j / 192, within = j - chunk * 192;
        half8_t h = {};
        if (within < 64) h[0] = (_Float16)(-4.0f);  // d=72
        *(half8_t*)(qh + (size_t)chunk * CHUNK_HALVES + 4608 + within * 8) = h;
    } else if (i < S4) {                            // k pads (own then enc)
        int j = i - S3;
        _Float16* base = (j < 196608) ? kh : ekh;
        int jj = (j < 196608) ? j : j - 196608;
        int chunk = jj / 192, within = jj - chunk * 192;
        half8_t h = {};
        if (within < 64) h[0] = (_Float16)1.0f;     // d=72
        *(half8_t*)(base + (size_t)chunk * CHUNK_HALVES + 4608 + within * 8) = h;
    } else if (i < S5) {                            // vt/evt ones row
        int j = i - S4;
        _Float16* base = (j < 8192) ? vth : evth;
        int jj = j & 8191;
        int chunk = jj >> 3, kq = jj & 7;
        half8_t o;
#pragma unroll
        for (int r = 0; r < 8; ++r) o[r] = (_Float16)1.0f;
        *(half8_t*)&base[(size_t)chunk * CHUNK_HALVES + kq * 768 + 576] = o;
    } else if (i < S6) {                            // loss slot zero
        *loss_out = 0.0f;
    } else if (i < S7) {                            // enc K convert
        int j = i - S6;
        int bh = j / 9216, r2 = j - bh * 9216;
        int nblk = r2 / 576, ii = r2 - nblk * 576;
        int n = ii / 9, dq = ii - n * 9;
        const float* s = ek + ((size_t)bh * PN + nblk * 64 + n) * PHD + dq * 8;
        _Float16* kd = ekh + ((size_t)bh * 16 + nblk) * CHUNK_HALVES;
        *(half8_t*)&kd[dq * 512 + n * 8] = cvt8(s);
    } else {                                        // enc V convert (gather)
        int j = i - S7;
        int bh = j / 9216, r2 = j - bh * 9216;
        int nblk = r2 / 576, ii = r2 - nblk * 576;
        int nq = ii / 72, d = ii - nq * 72;
        const float* vs = ev + ((size_t)bh * PN + nblk * 64) * PHD;
        _Float16* vd = evth + ((size_t)bh * 16 + nblk) * CHUNK_HALVES;
        half8_t h;
#pragma unroll
        for (int r = 0; r < 8; ++r)
            h[r] = (_Float16)vs[(nq * 8 + r) * PHD + d];
        *(half8_t*)&vd[nq * 768 + d * 8] = h;
    }
}

// ---------------------------------------------------------------------------
// MFMA f16 GEMM, TM x 128 tile, BK=64, grouped + bijective XCD swizzle.
// TM=256 (MODE 0, 512 thr, 8 waves 4Mx2N): 64 MFMA per barrier-pair,
//   staging/FLOP -25% vs 128^2 -- per-wave 64x64 tile code IDENTICAL.
// TM=128 (MODE 1, 256 thr, 4 waves 2Mx2N): proven 128^2 path.
// MODE 0: QKV epilogue -> blocked f16 q/k/vt (q pre-scaled by QSCALE)
// MODE 1: proj epilogue -> f32 (M,C) + bias, float4 stores
// ---------------------------------------------------------------------------
template<int MODE, int TM>
__global__ __launch_bounds__(TM == 256 ? 512 : 256) void gemm_mfma(
    const _Float16* __restrict__ A, const _Float16* __restrict__ Bm,
    const float* __restrict__ bias,
    _Float16* __restrict__ qh, _Float16* __restrict__ kh,
    _Float16* __restrict__ vth, float* __restrict__ out, int c_tiles)
{
    const int t    = threadIdx.x;
    const int lane = t & 63;
    const int w    = t >> 6;
    const int wm   = w >> 1, wn = w & 1;   // TM=256: wm 0..3; TM=128: wm 0..1
    const int lrow = lane & 15, quad = lane >> 4;

    // XCD-bijective swizzle: consecutive wg chunks land on one XCD's L2
    const int cpx = gridDim.x >> 3;          // grid % 8 == 0
    const int bid = blockIdx.x;
    const int wg  = (bid & 7) * cpx + (bid >> 3);

    const int per_group = c_tiles * 8;
    const int g  = wg / per_group;
    const int r_ = wg - g * per_group;
    const int m0 = (g * 8 + (r_ & 7)) * TM;
    const int c0 = (r_ >> 3) * 128;

    const bool tr = (MODE == 1) || (c0 < 2 * PC);   // q/k + proj transposed

    __shared__ _Float16 As[TM * 64];        // [kblock(8)][row(TM)][8]
    __shared__ _Float16 Bs[8192];           // [kblock(8)][row(128)][8]

    const _Float16* aBase = A  + (size_t)m0 * K_DIM;
    const _Float16* bBase = Bm + (size_t)c0 * K_DIM;

    float4v acc[4][4];
#pragma unroll
    for (int ti = 0; ti < 4; ++ti)
#pragma unroll
        for (int tj = 0; tj < 4; ++tj)
            acc[ti][tj] = (float4v){0.f, 0.f, 0.f, 0.f};

    for (int kb = 0; kb < K_DIM; kb += 64) {
        __syncthreads();
        if constexpr (TM == 256) {
            // 2048 A-cells + 1024 B-cells, 512 threads x 6
#pragma unroll
            for (int j = 0; j < 4; ++j) {        // A: a = j*512+t
                int a = j * 512 + t;
                int row = a & 255, kblk = a >> 8;
                load16_lds(aBase + (size_t)row * K_DIM + kb + kblk * 8, &As[a * 8]);
            }
#pragma unroll
            for (int j = 0; j < 2; ++j) {        // B: b = j*512+t
                int b = j * 512 + t;
                int row = b & 127, kblk = b >> 7;
                load16_lds(bBase + (size_t)row * K_DIM + kb + kblk * 8, &Bs[b * 8]);
            }
        } else {
            // 1024 A-cells + 1024 B-cells, 256 threads x 8
#pragma unroll
            for (int j = 0; j < 4; ++j) {
                int idx = j * 256 + t;           // idx = kblk*128 + row
                int row = idx & 127, kblk = idx >> 7;
                load16_lds(aBase + (size_t)row * K_DIM + kb + kblk * 8, &As[idx * 8]);
                load16_lds(bBase + (size_t)row * K_DIM + kb + kblk * 8, &Bs[idx * 8]);
            }
        }
        __syncthreads();
#pragma unroll
        for (int s = 0; s < 2; ++s) {
            half8_t af[4], bf[4];
#pragma unroll
            for (int ti = 0; ti < 4; ++ti)
                af[ti] = *(const half8_t*)&As[(((s * 4 + quad) * TM) + wm * 64 + ti * 16 + lrow) * 8];
#pragma unroll
            for (int tj = 0; tj < 4; ++tj)
                bf[tj] = *(const half8_t*)&Bs[(((s * 4 + quad) * 128) + wn * 64 + tj * 16 + lrow) * 8];
            if (tr) {
#pragma unroll
                for (int ti = 0; ti < 4; ++ti)
#pragma unroll
                    for (int tj = 0; tj < 4; ++tj)
                        acc[ti][tj] = __builtin_amdgcn_mfma_f32_16x16x32_f16(
                            bf[tj], af[ti], acc[ti][tj], 0, 0, 0);
            } else {
#pragma unroll
                for (int ti = 0; ti < 4; ++ti)
#pragma unroll
                    for (int tj = 0; tj < 4; ++tj)
                        acc[ti][tj] = __builtin_amdgcn_mfma_f32_16x16x32_f16(
                            af[ti], bf[tj], acc[ti][tj], 0, 0, 0);
            }
        }
    }

    if (MODE == 1) {
#pragma unroll
        for (int tj = 0; tj < 4; ++tj) {
            int cg = c0 + wn * 64 + tj * 16 + quad * 4;
            float4v bv = *(const float4v*)&bias[cg];
#pragma unroll
            for (int ti = 0; ti < 4; ++ti) {
                int m = m0 + wm * 64 + ti * 16 + lrow;
                float4v o;
#pragma unroll
                for (int r = 0; r < 4; ++r) o[r] = acc[ti][tj][r] + bv[r];
                *(float4v*)&out[(size_t)m * PC + cg] = o;
            }
        }
    } else if (tr) {
        // q/k: lane owns n (fixed), d-group of 4 (never straddles a head)
        const int jq = c0 / PC;               // 0 = q, 1 = k (uniform per block)
        const float mulv = (jq == 0) ? QSCALE : 1.f;
        _Float16* dstp = (jq == 0) ? qh : kh;
#pragma unroll
        for (int tj = 0; tj < 4; ++tj) {
            int cg  = c0 + wn * 64 + tj * 16 + quad * 4;
            int rem = cg - jq * PC;
            int h   = rem / PHD;
            int ds  = rem - h * PHD;          // multiple of 4
            float4v bv = *(const float4v*)&bias[cg];
#pragma unroll
            for (int ti = 0; ti < 4; ++ti) {
                int m = m0 + wm * 64 + ti * 16 + lrow;
                int b = m >> 10, n = m & 1023;
                size_t chunk = ((size_t)(b * PH + h) * 16 + (n >> 6)) * CHUNK_HALVES;
                half4_t hv;
#pragma unroll
                for (int r = 0; r < 4; ++r)
                    hv[r] = (_Float16)((acc[ti][tj][r] + bv[r]) * mulv);
                *(half4_t*)&dstp[chunk + (ds >> 3) * 512 + (n & 63) * 8 + (ds & 7)] = hv;
            }
        }
    } else {
        // v: lane owns d (fixed), n-group of 4 -> contiguous in vt layout
#pragma unroll
        for (int tj = 0; tj < 4; ++tj) {
            int c   = c0 + wn * 64 + tj * 16 + lrow;
            int rem = c - 2 * PC;
            int h   = rem / PHD;
            int d   = rem - h * PHD;
            float bv = bias[c];
#pragma unroll
            for (int ti = 0; ti < 4; ++ti) {
                int mg = m0 + wm * 64 + ti * 16 + quad * 4;
                int b = mg >> 10, n = mg & 1023;
                size_t chunk = ((size_t)(b * PH + h) * 16 + (n >> 6)) * CHUNK_HALVES;
                half4_t hv;
#pragma unroll
                for (int r = 0; r < 4; ++r)
                    hv[r] = (_Float16)(acc[ti][tj][r] + bv);
                *(half4_t*)&vth[chunk + ((n & 63) >> 3) * 768 + d * 8 + (n & 7)] = hv;
            }
        }
    }
}

// ---------------------------------------------------------------------------
// One transposed flash-attention step, FIXED-SHIFT softmax (base-2):
//   S^T - 4 = K Q^T (shift folded into pad dims d=72: q=-4, k=1);
//   P = exp2(accS) directly; P -> B-layout via 4 ds_write_b64;
//   O^T += V^T P^T (ones-row at d=72 accumulates l in O[4][0], quad 2).
// No setprio (round 6: -3% in this regime).
// ---------------------------------------------------------------------------
__device__ __forceinline__ void attn_step(
    const half8_t* qf, const _Float16* Ks, const _Float16* Vts, _Float16* Pw,
    float4v* O, int ln, int quad)
{
    float4v accS[4];
#pragma unroll
    for (int ct = 0; ct < 4; ++ct) accS[ct] = (float4v){0.f, 0.f, 0.f, 0.f};
#pragma unroll
    for (int ks = 0; ks < 3; ++ks) {
#pragma unroll
        for (int ct = 0; ct < 4; ++ct) {
            half8_t kf = *(const half8_t*)&Ks[(((ks * 4 + quad) * 64) + ct * 16 + ln) * 8];
            accS[ct] = __builtin_amdgcn_mfma_f32_16x16x32_f16(kf, qf[ks], accS[ct], 0, 0, 0);
        }
    }

    const int pbase = (quad >> 1) * 128 + ln * 8 + (quad & 1) * 4;
#pragma unroll
    for (int ct = 0; ct < 4; ++ct) {
        half4_t pk;
#pragma unroll
        for (int r = 0; r < 4; ++r)
            pk[r] = (_Float16)exp2f(accS[ct][r]);
        *(half4_t*)&Pw[pbase + ct * 256] = pk;
    }

#pragma unroll
    for (int ks = 0; ks < 2; ++ks) {
        half8_t pf = *(const half8_t*)&Pw[(ks * 4 + quad) * 128 + ln * 8];
#pragma unroll
        for (int ct = 0; ct < 5; ++ct) {
            half8_t vf = *(const half8_t*)&Vts[(((ks * 4 + quad) * 96) + ct * 16 + ln) * 8];
            O[ct] = __builtin_amdgcn_mfma_f32_16x16x32_f16(vf, pf, O[ct], 0, 0, 0);
        }
    }
}

// ---------------------------------------------------------------------------
// Fused dual-pass flash attention — round-5 chassis, best measured (83.3 us):
// 256 thr, 1024 blocks, single K/V buffer staged by global_load_lds between
// two barriers, 33 KB LDS -> 4 blk/CU (inter-block wave overlap hides
// staging).  Structural pushes (dbuf, dual-Q, setprio) all measured null or
// negative in rounds 4/6/7 -- do not touch.
// ---------------------------------------------------------------------------
__global__ __launch_bounds__(256, 4) void attn_fused(
    const _Float16* __restrict__ qh, const _Float16* __restrict__ kh,
    const _Float16* __restrict__ vth,
    const _Float16* __restrict__ ekh, const _Float16* __restrict__ evth,
    _Float16* __restrict__ xouth, float* __restrict__ loss_out)
{
    const int t = threadIdx.x;
    const int lane = t & 63;
    const int w = t >> 6;
    const int ln = lane & 15;
    const int quad = lane >> 4;

    const int lid  = blockIdx.x;             // 1024 blocks
    const int bh   = (lid & 7) * 8 + ((lid >> 3) >> 4);
    const int nblk = (lid >> 3) & 15;

    __shared__ _Float16 Ks[CHUNK_HALVES];
    __shared__ _Float16 Vs[CHUNK_HALVES];
    __shared__ _Float16 Ps[4096];   // per-wave 1024-half P^T region
    __shared__ float red[256];

    _Float16* Pw = Ps + w * 1024;

    // Q fragments straight to registers (wave-private rows)
    const _Float16* qc = qh + ((size_t)bh * 16 + nblk) * CHUNK_HALVES;
    half8_t qf[3];
#pragma unroll
    for (int ks = 0; ks < 3; ++ks)
        qf[ks] = *(const half8_t*)&qc[(((ks * 4 + quad) * 64) + w * 16 + ln) * 8];

    const _Float16* kbo = kh   + (size_t)bh * HEAD_HALVES;
    const _Float16* vbo = vth  + (size_t)bh * HEAD_HALVES;
    const _Float16* kbe = ekh  + (size_t)bh * HEAD_HALVES;
    const _Float16* vbe = evth + (size_t)bh * HEAD_HALVES;

    float4v Oo[5], Oe[5];
#pragma unroll
    for (int ct = 0; ct < 5; ++ct) {
        Oo[ct] = (float4v){0.f, 0.f, 0.f, 0.f};
        Oe[ct] = (float4v){0.f, 0.f, 0.f, 0.f};
    }

    // pass 0: own K/V
    for (int kt = 0; kt < 16; ++kt) {
        const _Float16* kc = kbo + (size_t)kt * CHUNK_HALVES;
        const _Float16* vc = vbo + (size_t)kt * CHUNK_HALVES;
        __syncthreads();
#pragma unroll
        for (int i = 0; i < 3; ++i) {
            int u = i * 256 + t;
            load16_lds(kc + u * 8, &Ks[u * 8]);
            load16_lds(vc + u * 8, &Vs[u * 8]);
        }
        __syncthreads();
        attn_step(qf, Ks, Vs, Pw, Oo, ln, quad);
    }
    // pass 1: encoder K/V
    for (int kt = 0; kt < 16; ++kt) {
        const _Float16* kc = kbe + (size_t)kt * CHUNK_HALVES;
        const _Float16* vc = vbe + (size_t)kt * CHUNK_HALVES;
        __syncthreads();
#pragma unroll
        for (int i = 0; i < 3; ++i) {
            int u = i * 256 + t;
            load16_lds(kc + u * 8, &Ks[u * 8]);
            load16_lds(vc + u * 8, &Vs[u * 8]);
        }
        __syncthreads();
        attn_step(qf, Ks, Vs, Pw, Oe, ln, quad);
    }

    // l lives in O[4][0] of quad-2 lanes (the ones-row at d=72)
    float l_o = __shfl(Oo[4][0], 32 + ln);
    float l_e = __shfl(Oe[4][0], 32 + ln);
    const float inv_o = 1.0f / l_o;
    const float inv_e = 1.0f / l_e;

    const int b = bh >> 4, h = bh & 15;
    const int nrow = nblk * 64 + w * 16 + ln;   // this lane's Q-row

    float lacc = 0.f;
    const size_t rowbase = (size_t)(b * PN + nrow) * PC + h * PHD;
#pragma unroll
    for (int ct = 0; ct < 5; ++ct) {
        int d0 = ct * 16 + quad * 4;
        if (d0 < PHD) {                  // ct=4: only quads 0,1 valid
            half4_t oh;
#pragma unroll
            for (int r = 0; r < 4; ++r) {
                float own = Oo[ct][r] * inv_o;
                oh[r] = (_Float16)own;
                float df = own - Oe[ct][r] * inv_e;
                lacc += df * df;
            }
            *(half4_t*)&xouth[rowbase + d0] = oh;   // 8B aligned
        }
    }

    red[t] = lacc;
    __syncthreads();
    for (int off = 128; off > 0; off >>= 1) {
        if (t < off) red[t] += red[t + off];
        __syncthreads();
    }
    if (t == 0) atomicAdd(loss_out, red[0] * (1.0f / (float)OUT_ELEMS));
}

// ---------------------------------------------------------------------------
extern "C" void kernel_launch(void* const* d_in, const int* in_sizes, int n_in,
                              void* d_out, int out_size, void* d_ws, size_t ws_size,
                              hipStream_t stream)
{
    const float* x      = (const float*)d_in[0];
    const float* enc_k  = (const float*)d_in[1];
    const float* enc_v  = (const float*)d_in[2];
    const float* qkv_w  = (const float*)d_in[3];
    const float* qkv_b  = (const float*)d_in[4];
    const float* proj_w = (const float*)d_in[5];
    const float* proj_b = (const float*)d_in[6];

    float* out = (float*)d_out;

    _Float16* x_h     = (_Float16*)d_ws;
    _Float16* qkvw_h  = x_h + OUT_ELEMS;
    _Float16* projw_h = qkvw_h + (size_t)QKV_COLS * PC;
    _Float16* xout_h  = projw_h + (size_t)PC * PC;
    _Float16* q_h     = xout_h + OUT_ELEMS;
    _Float16* k_h     = q_h  + BUF_HALVES;
    _Float16* vt_h    = k_h  + BUF_HALVES;
    _Float16* ek_h    = vt_h + BUF_HALVES;
    _Float16* evt_h   = ek_h + BUF_HALVES;

    // 0. ONE prep kernel: conversions + pad constants + enc layouts + loss=0
    prep_all<<<11873, 256, 0, stream>>>(
        x, qkv_w, proj_w, enc_k, enc_v,
        x_h, qkvw_h, projw_h, q_h, k_h, ek_h, vt_h, evt_h, out + OUT_ELEMS);

    // 1. QKV projection (256x128 tiles, 512 thr) -> blocked f16 q/k/vt
    gemm_mfma<0, 256><<<(QKV_COLS / 128) * ((PB * PN) / 256), 512, 0, stream>>>(
        x_h, qkvw_h, qkv_b, q_h, k_h, vt_h, nullptr, QKV_COLS / 128);

    // 2. Fused own+enc attention (round-5 chassis) -> xout_h + loss
    attn_fused<<<16 * BH, 256, 0, stream>>>(
        q_h, k_h, vt_h, ek_h, evt_h, xout_h, out + OUT_ELEMS);

    // 3. Output projection (128x128 tiles, transposed, float4 stores)
    gemm_mfma<1, 128><<<(PC / 128) * ((PB * PN) / 128), 256, 0, stream>>>(
        xout_h, projw_h, proj_b, nullptr, nullptr, nullptr, out, PC / 128);
}

// Round 9
// 310.508 us; speedup vs baseline: 1.0916x; 1.0916x over previous
//
#include <hip/hip_runtime.h>
#include <hip/hip_bf16.h>

// Problem constants: B=4, N=1024, C=1152, H=16, hd=72
#define PB 4
#define PN 1024
#define PC 1152
#define PH 16
#define PHD 72
#define BH 64
#define QKV_COLS 3456
#define OUT_ELEMS ((size_t)PB*PN*PC)   // 4718592
#define K_DIM 1152

// Blocked f16 layouts (per (bh, 64-row chunk), 6144 halves = 12288 B):
//  q/k:  [dq(12)][row(64)][8]   element (n,d) -> (d>>3)*512 + (n&63)*8 + (d&7)
//  vt :  [kq(8)][hd(96)][8]     element (n,d) -> ((n&63)>>3)*768 + d*8 + (n&7)
// Pad-dim tricks (prep_all):
//  q[d=72] = -4.0, k[d=72] = 1.0 (own + enc)  -> QK^T MFMA emits S - 4
//    directly (fixed base-2 softmax shift; exact softmax identity).
//  vt[d=72] = 1.0                             -> PV MFMA accumulates the
//    softmax denominator l in O[4][0] of quad-2 lanes for free.
#define CHUNK_HALVES 6144
#define HEAD_HALVES (16*CHUNK_HALVES)       // 98304
#define BUF_HALVES ((size_t)BH*HEAD_HALVES) // 6291456 per buffer

typedef _Float16 half8_t __attribute__((ext_vector_type(8)));
typedef _Float16 half4_t __attribute__((ext_vector_type(4)));
typedef float float4v __attribute__((ext_vector_type(4)));

// q pre-scale: hd^-0.5 * log2(e)  (softmax computed base-2, exactly equivalent)
#define QSCALE (0.11785113019775792f * 1.4426950408889634f)

__device__ __forceinline__ void load16_lds(const _Float16* g, _Float16* l) {
    __builtin_amdgcn_global_load_lds(
        (const __attribute__((address_space(1))) void*)g,
        (__attribute__((address_space(3))) void*)l, 16, 0, 0);
}

__device__ __forceinline__ half8_t cvt8(const float* p) {
    float4 a = *(const float4*)p;
    float4 b = *(const float4*)(p + 4);
    half8_t h;
    h[0] = (_Float16)a.x; h[1] = (_Float16)a.y; h[2] = (_Float16)a.z; h[3] = (_Float16)a.w;
    h[4] = (_Float16)b.x; h[5] = (_Float16)b.y; h[6] = (_Float16)b.z; h[7] = (_Float16)b.w;
    return h;
}

// ---------------------------------------------------------------------------
// ONE prep kernel for everything that precedes the GEMMs:
//  [0,S0):    x f32->f16              [S0,S1): qkv_w      [S1,S2): proj_w
//  [S2,S3):   q pads (d=72:-4, 73..95:0)
//  [S3,S4):   k pads own+enc (d=72:1, 73..95:0)
//  [S4,S5):   vt/evt ones row d=72
//  [S5,S6):   loss slot zero (1 task)
//  [S6,S7):   enc_k -> blocked k layout (16-B stores)
//  [S7,S8):   enc_v -> blocked vt layout (lane-coalesced gather, 16-B stores)
// ---------------------------------------------------------------------------
#define S0 589824
#define S1 1087488
#define S2 1253376
#define S3 1449984
#define S4 1843200
#define S5 1859584
#define S6 1859585
#define S7 2449409
#define S8 3039233

__global__ __launch_bounds__(256) void prep_all(
    const float* __restrict__ x, const float* __restrict__ qkv_w,
    const float* __restrict__ proj_w,
    const float* __restrict__ ek, const float* __restrict__ ev,
    _Float16* __restrict__ xh, _Float16* __restrict__ qkvwh,
    _Float16* __restrict__ projwh,
    _Float16* __restrict__ qh, _Float16* __restrict__ kh, _Float16* __restrict__ ekh,
    _Float16* __restrict__ vth, _Float16* __restrict__ evth,
    float* __restrict__ loss_out)
{
    int i = blockIdx.x * 256 + threadIdx.x;
    if (i >= S8) return;

    if (i < S0) {                                   // x conversion
        ((half8_t*)xh)[i] = cvt8(x + (size_t)i * 8);
    } else if (i < S1) {                            // qkv_w conversion
        int j = i - S0;
        ((half8_t*)qkvwh)[j] = cvt8(qkv_w + (size_t)j * 8);
    } else if (i < S2) {                            // proj_w conversion
        int j = i - S1;
        ((half8_t*)projwh)[j] = cvt8(proj_w + (size_t)j * 8);
    } else if (i < S3) {                            // q pads
        int j = i - S2;
        int chunk = j / 192, within = j - chunk * 192;
        half8_t h = {};
        if (within < 64) h[0] = (_Float16)(-4.0f);  // d=72
        *(half8_t*)(qh + (size_t)chunk * CHUNK_HALVES + 4608 + within * 8) = h;
    } else if (i < S4) {                            // k pads (own then enc)
        int j = i - S3;
        _Float16* base = (j < 196608) ? kh : ekh;
        int jj = (j < 196608) ? j : j - 196608;
        int chunk = jj / 192, within = jj - chunk * 192;
        half8_t h = {};
        if (within < 64) h[0] = (_Float16)1.0f;     // d=72
        *(half8_t*)(base + (size_t)chunk * CHUNK_HALVES + 4608 + within * 8) = h;
    } else if (i < S5) {                            // vt/evt ones row
        int j = i - S4;
        _Float16* base = (j < 8192) ? vth : evth;
        int jj = j & 8191;
        int chunk = jj >> 3, kq = jj & 7;
        half8_t o;
#pragma unroll
        for (int r = 0; r < 8; ++r) o[r] = (_Float16)1.0f;
        *(half8_t*)&base[(size_t)chunk * CHUNK_HALVES + kq * 768 + 576] = o;
    } else if (i < S6) {                            // loss slot zero
        *loss_out = 0.0f;
    } else if (i < S7) {                            // enc K convert
        int j = i - S6;
        int bh = j / 9216, r2 = j - bh * 9216;
        int nblk = r2 / 576, ii = r2 - nblk * 576;
        int n = ii / 9, dq = ii - n * 9;
        const float* s = ek + ((size_t)bh * PN + nblk * 64 + n) * PHD + dq * 8;
        _Float16* kd = ekh + ((size_t)bh * 16 + nblk) * CHUNK_HALVES;
        *(half8_t*)&kd[dq * 512 + n * 8] = cvt8(s);
    } else {                                        // enc V convert (gather)
        int j = i - S7;
        int bh = j / 9216, r2 = j - bh * 9216;
        int nblk = r2 / 576, ii = r2 - nblk * 576;
        int nq = ii / 72, d = ii - nq * 72;
        const float* vs = ev + ((size_t)bh * PN + nblk * 64) * PHD;
        _Float16* vd = evth + ((size_t)bh * 16 + nblk) * CHUNK_HALVES;
        half8_t h;
#pragma unroll
        for (int r = 0; r < 8; ++r)
            h[r] = (_Float16)vs[(nq * 8 + r) * PHD + d];
        *(half8_t*)&vd[nq * 768 + d * 8] = h;
    }
}

// ---------------------------------------------------------------------------
// MFMA f16 GEMM, TM x 128 tile, BK=64, threads = 2*TM, grouped + bijective
// XCD swizzle (grids 864 / 576, both % 8 == 0).
// TM=128 (MODE 0, 256 thr, 4 waves 2Mx2N): proven best for the big GEMM
//   (round 8: TM=256 regressed -29% -- occupancy loss beats staging savings).
// TM=64  (MODE 1, 128 thr, 2 waves 1Mx2N): doubles grid for the small GEMM
//   (288 -> 576 blocks) to smooth the 1.125-blocks/CU tail (1.78x -> 1.33x).
// MODE 0: QKV epilogue -> blocked f16 q/k/vt (q pre-scaled by QSCALE)
// MODE 1: proj epilogue -> f32 (M,C) + bias, float4 stores
// ---------------------------------------------------------------------------
template<int MODE, int TM>
__global__ __launch_bounds__(2 * TM) void gemm_mfma(
    const _Float16* __restrict__ A, const _Float16* __restrict__ Bm,
    const float* __restrict__ bias,
    _Float16* __restrict__ qh, _Float16* __restrict__ kh,
    _Float16* __restrict__ vth, float* __restrict__ out, int c_tiles)
{
    constexpr int THREADS = 2 * TM;
    const int t    = threadIdx.x;
    const int lane = t & 63;
    const int w    = t >> 6;
    const int wm   = w >> 1, wn = w & 1;   // TM=64: wm==0 always
    const int lrow = lane & 15, quad = lane >> 4;

    // XCD-bijective swizzle: consecutive wg chunks land on one XCD's L2
    const int cpx = gridDim.x >> 3;          // grid % 8 == 0
    const int bid = blockIdx.x;
    const int wg  = (bid & 7) * cpx + (bid >> 3);

    const int per_group = c_tiles * 8;
    const int g  = wg / per_group;
    const int r_ = wg - g * per_group;
    const int m0 = (g * 8 + (r_ & 7)) * TM;
    const int c0 = (r_ >> 3) * 128;

    const bool tr = (MODE == 1) || (c0 < 2 * PC);   // q/k + proj transposed

    __shared__ _Float16 As[TM * 64];        // [kblock(8)][row(TM)][8]
    __shared__ _Float16 Bs[8192];           // [kblock(8)][row(128)][8]

    const _Float16* aBase = A  + (size_t)m0 * K_DIM;
    const _Float16* bBase = Bm + (size_t)c0 * K_DIM;

    float4v acc[4][4];
#pragma unroll
    for (int ti = 0; ti < 4; ++ti)
#pragma unroll
        for (int tj = 0; tj < 4; ++tj)
            acc[ti][tj] = (float4v){0.f, 0.f, 0.f, 0.f};

    for (int kb = 0; kb < K_DIM; kb += 64) {
        __syncthreads();
        // A: TM*8 cells = 4 loads/thread (any TM)
#pragma unroll
        for (int j = 0; j < 4; ++j) {
            int a = j * THREADS + t;
            int row = a % TM, kblk = a / TM;
            load16_lds(aBase + (size_t)row * K_DIM + kb + kblk * 8, &As[a * 8]);
        }
        // B: 1024 cells = 512/TM loads/thread
#pragma unroll
        for (int j = 0; j < 512 / TM; ++j) {
            int b = j * THREADS + t;
            int row = b & 127, kblk = b >> 7;
            load16_lds(bBase + (size_t)row * K_DIM + kb + kblk * 8, &Bs[b * 8]);
        }
        __syncthreads();
#pragma unroll
        for (int s = 0; s < 2; ++s) {
            half8_t af[4], bf[4];
#pragma unroll
            for (int ti = 0; ti < 4; ++ti)
                af[ti] = *(const half8_t*)&As[(((s * 4 + quad) * TM) + wm * 64 + ti * 16 + lrow) * 8];
#pragma unroll
            for (int tj = 0; tj < 4; ++tj)
                bf[tj] = *(const half8_t*)&Bs[(((s * 4 + quad) * 128) + wn * 64 + tj * 16 + lrow) * 8];
            if (tr) {
#pragma unroll
                for (int ti = 0; ti < 4; ++ti)
#pragma unroll
                    for (int tj = 0; tj < 4; ++tj)
                        acc[ti][tj] = __builtin_amdgcn_mfma_f32_16x16x32_f16(
                            bf[tj], af[ti], acc[ti][tj], 0, 0, 0);
            } else {
#pragma unroll
                for (int ti = 0; ti < 4; ++ti)
#pragma unroll
                    for (int tj = 0; tj < 4; ++tj)
                        acc[ti][tj] = __builtin_amdgcn_mfma_f32_16x16x32_f16(
                            af[ti], bf[tj], acc[ti][tj], 0, 0, 0);
            }
        }
    }

    if (MODE == 1) {
#pragma unroll
        for (int tj = 0; tj < 4; ++tj) {
            int cg = c0 + wn * 64 + tj * 16 + quad * 4;
            float4v bv = *(const float4v*)&bias[cg];
#pragma unroll
            for (int ti = 0; ti < 4; ++ti) {
                int m = m0 + wm * 64 + ti * 16 + lrow;
                float4v o;
#pragma unroll
                for (int r = 0; r < 4; ++r) o[r] = acc[ti][tj][r] + bv[r];
                *(float4v*)&out[(size_t)m * PC + cg] = o;
            }
        }
    } else if (tr) {
        // q/k: lane owns n (fixed), d-group of 4 (never straddles a head)
        const int jq = c0 / PC;               // 0 = q, 1 = k (uniform per block)
        const float mulv = (jq == 0) ? QSCALE : 1.f;
        _Float16* dstp = (jq == 0) ? qh : kh;
#pragma unroll
        for (int tj = 0; tj < 4; ++tj) {
            int cg  = c0 + wn * 64 + tj * 16 + quad * 4;
            int rem = cg - jq * PC;
            int h   = rem / PHD;
            int ds  = rem - h * PHD;          // multiple of 4
            float4v bv = *(const float4v*)&bias[cg];
#pragma unroll
            for (int ti = 0; ti < 4; ++ti) {
                int m = m0 + wm * 64 + ti * 16 + lrow;
                int b = m >> 10, n = m & 1023;
                size_t chunk = ((size_t)(b * PH + h) * 16 + (n >> 6)) * CHUNK_HALVES;
                half4_t hv;
#pragma unroll
                for (int r = 0; r < 4; ++r)
                    hv[r] = (_Float16)((acc[ti][tj][r] + bv[r]) * mulv);
                *(half4_t*)&dstp[chunk + (ds >> 3) * 512 + (n & 63) * 8 + (ds & 7)] = hv;
            }
        }
    } else {
        // v: lane owns d (fixed), n-group of 4 -> contiguous in vt layout
#pragma unroll
        for (int tj = 0; tj < 4; ++tj) {
            int c   = c0 + wn * 64 + tj * 16 + lrow;
            int rem = c - 2 * PC;
            int h   = rem / PHD;
            int d   = rem - h * PHD;
            float bv = bias[c];
#pragma unroll
            for (int ti = 0; ti < 4; ++ti) {
                int mg = m0 + wm * 64 + ti * 16 + quad * 4;
                int b = mg >> 10, n = mg & 1023;
                size_t chunk = ((size_t)(b * PH + h) * 16 + (n >> 6)) * CHUNK_HALVES;
                half4_t hv;
#pragma unroll
                for (int r = 0; r < 4; ++r)
                    hv[r] = (_Float16)(acc[ti][tj][r] + bv);
                *(half4_t*)&vth[chunk + ((n & 63) >> 3) * 768 + d * 8 + (n & 7)] = hv;
            }
        }
    }
}

// ---------------------------------------------------------------------------
// One transposed flash-attention step, FIXED-SHIFT softmax (base-2):
//   S^T - 4 = K Q^T (shift folded into pad dims d=72: q=-4, k=1);
//   P = exp2(accS) directly; P -> B-layout via 4 ds_write_b64;
//   O^T += V^T P^T (ones-row at d=72 accumulates l in O[4][0], quad 2).
// ---------------------------------------------------------------------------
__device__ __forceinline__ void attn_step(
    const half8_t* qf, const _Float16* Ks, const _Float16* Vts, _Float16* Pw,
    float4v* O, int ln, int quad)
{
    float4v accS[4];
#pragma unroll
    for (int ct = 0; ct < 4; ++ct) accS[ct] = (float4v){0.f, 0.f, 0.f, 0.f};
#pragma unroll
    for (int ks = 0; ks < 3; ++ks) {
#pragma unroll
        for (int ct = 0; ct < 4; ++ct) {
            half8_t kf = *(const half8_t*)&Ks[(((ks * 4 + quad) * 64) + ct * 16 + ln) * 8];
            accS[ct] = __builtin_amdgcn_mfma_f32_16x16x32_f16(kf, qf[ks], accS[ct], 0, 0, 0);
        }
    }

    const int pbase = (quad >> 1) * 128 + ln * 8 + (quad & 1) * 4;
#pragma unroll
    for (int ct = 0; ct < 4; ++ct) {
        half4_t pk;
#pragma unroll
        for (int r = 0; r < 4; ++r)
            pk[r] = (_Float16)exp2f(accS[ct][r]);
        *(half4_t*)&Pw[pbase + ct * 256] = pk;
    }

#pragma unroll
    for (int ks = 0; ks < 2; ++ks) {
        half8_t pf = *(const half8_t*)&Pw[(ks * 4 + quad) * 128 + ln * 8];
#pragma unroll
        for (int ct = 0; ct < 5; ++ct) {
            half8_t vf = *(const half8_t*)&Vts[(((ks * 4 + quad) * 96) + ct * 16 + ln) * 8];
            O[ct] = __builtin_amdgcn_mfma_f32_16x16x32_f16(vf, pf, O[ct], 0, 0, 0);
        }
    }
}

// ---------------------------------------------------------------------------
// Fused dual-pass flash attention — round-5 chassis, best measured (83.3 us):
// 256 thr, 1024 blocks, single K/V buffer staged by global_load_lds between
// two barriers, 33 KB LDS -> 4 blk/CU (inter-block wave overlap hides
// staging).  Structural pushes (dbuf, dual-Q, setprio, 256-tile) all measured
// null or negative in rounds 4/6/7/8 -- locked.
// ---------------------------------------------------------------------------
__global__ __launch_bounds__(256, 4) void attn_fused(
    const _Float16* __restrict__ qh, const _Float16* __restrict__ kh,
    const _Float16* __restrict__ vth,
    const _Float16* __restrict__ ekh, const _Float16* __restrict__ evth,
    _Float16* __restrict__ xouth, float* __restrict__ loss_out)
{
    const int t = threadIdx.x;
    const int lane = t & 63;
    const int w = t >> 6;
    const int ln = lane & 15;
    const int quad = lane >> 4;

    const int lid  = blockIdx.x;             // 1024 blocks
    const int bh   = (lid & 7) * 8 + ((lid >> 3) >> 4);
    const int nblk = (lid >> 3) & 15;

    __shared__ _Float16 Ks[CHUNK_HALVES];
    __shared__ _Float16 Vs[CHUNK_HALVES];
    __shared__ _Float16 Ps[4096];   // per-wave 1024-half P^T region
    __shared__ float red[256];

    _Float16* Pw = Ps + w * 1024;

    // Q fragments straight to registers (wave-private rows)
    const _Float16* qc = qh + ((size_t)bh * 16 + nblk) * CHUNK_HALVES;
    half8_t qf[3];
#pragma unroll
    for (int ks = 0; ks < 3; ++ks)
        qf[ks] = *(const half8_t*)&qc[(((ks * 4 + quad) * 64) + w * 16 + ln) * 8];

    const _Float16* kbo = kh   + (size_t)bh * HEAD_HALVES;
    const _Float16* vbo = vth  + (size_t)bh * HEAD_HALVES;
    const _Float16* kbe = ekh  + (size_t)bh * HEAD_HALVES;
    const _Float16* vbe = evth + (size_t)bh * HEAD_HALVES;

    float4v Oo[5], Oe[5];
#pragma unroll
    for (int ct = 0; ct < 5; ++ct) {
        Oo[ct] = (float4v){0.f, 0.f, 0.f, 0.f};
        Oe[ct] = (float4v){0.f, 0.f, 0.f, 0.f};
    }

    // pass 0: own K/V
    for (int kt = 0; kt < 16; ++kt) {
        const _Float16* kc = kbo + (size_t)kt * CHUNK_HALVES;
        const _Float16* vc = vbo + (size_t)kt * CHUNK_HALVES;
        __syncthreads();
#pragma unroll
        for (int i = 0; i < 3; ++i) {
            int u = i * 256 + t;
            load16_lds(kc + u * 8, &Ks[u * 8]);
            load16_lds(vc + u * 8, &Vs[u * 8]);
        }
        __syncthreads();
        attn_step(qf, Ks, Vs, Pw, Oo, ln, quad);
    }
    // pass 1: encoder K/V
    for (int kt = 0; kt < 16; ++kt) {
        const _Float16* kc = kbe + (size_t)kt * CHUNK_HALVES;
        const _Float16* vc = vbe + (size_t)kt * CHUNK_HALVES;
        __syncthreads();
#pragma unroll
        for (int i = 0; i < 3; ++i) {
            int u = i * 256 + t;
            load16_lds(kc + u * 8, &Ks[u * 8]);
            load16_lds(vc + u * 8, &Vs[u * 8]);
        }
        __syncthreads();
        attn_step(qf, Ks, Vs, Pw, Oe, ln, quad);
    }

    // l lives in O[4][0] of quad-2 lanes (the ones-row at d=72)
    float l_o = __shfl(Oo[4][0], 32 + ln);
    float l_e = __shfl(Oe[4][0], 32 + ln);
    const float inv_o = 1.0f / l_o;
    const float inv_e = 1.0f / l_e;

    const int b = bh >> 4, h = bh & 15;
    const int nrow = nblk * 64 + w * 16 + ln;   // this lane's Q-row

    float lacc = 0.f;
    const size_t rowbase = (size_t)(b * PN + nrow) * PC + h * PHD;
#pragma unroll
    for (int ct = 0; ct < 5; ++ct) {
        int d0 = ct * 16 + quad * 4;
        if (d0 < PHD) {                  // ct=4: only quads 0,1 valid
            half4_t oh;
#pragma unroll
            for (int r = 0; r < 4; ++r) {
                float own = Oo[ct][r] * inv_o;
                oh[r] = (_Float16)own;
                float df = own - Oe[ct][r] * inv_e;
                lacc += df * df;
            }
            *(half4_t*)&xouth[rowbase + d0] = oh;   // 8B aligned
        }
    }

    red[t] = lacc;
    __syncthreads();
    for (int off = 128; off > 0; off >>= 1) {
        if (t < off) red[t] += red[t + off];
        __syncthreads();
    }
    if (t == 0) atomicAdd(loss_out, red[0] * (1.0f / (float)OUT_ELEMS));
}

// ---------------------------------------------------------------------------
extern "C" void kernel_launch(void* const* d_in, const int* in_sizes, int n_in,
                              void* d_out, int out_size, void* d_ws, size_t ws_size,
                              hipStream_t stream)
{
    const float* x      = (const float*)d_in[0];
    const float* enc_k  = (const float*)d_in[1];
    const float* enc_v  = (const float*)d_in[2];
    const float* qkv_w  = (const float*)d_in[3];
    const float* qkv_b  = (const float*)d_in[4];
    const float* proj_w = (const float*)d_in[5];
    const float* proj_b = (const float*)d_in[6];

    float* out = (float*)d_out;

    _Float16* x_h     = (_Float16*)d_ws;
    _Float16* qkvw_h  = x_h + OUT_ELEMS;
    _Float16* projw_h = qkvw_h + (size_t)QKV_COLS * PC;
    _Float16* xout_h  = projw_h + (size_t)PC * PC;
    _Float16* q_h     = xout_h + OUT_ELEMS;
    _Float16* k_h     = q_h  + BUF_HALVES;
    _Float16* vt_h    = k_h  + BUF_HALVES;
    _Float16* ek_h    = vt_h + BUF_HALVES;
    _Float16* evt_h   = ek_h + BUF_HALVES;

    // 0. ONE prep kernel: conversions + pad constants + enc layouts + loss=0
    prep_all<<<11873, 256, 0, stream>>>(
        x, qkv_w, proj_w, enc_k, enc_v,
        x_h, qkvw_h, projw_h, q_h, k_h, ek_h, vt_h, evt_h, out + OUT_ELEMS);

    // 1. QKV projection (proven 128x128, grid 864) -> blocked f16 q/k/vt
    gemm_mfma<0, 128><<<(QKV_COLS / 128) * ((PB * PN) / 128), 256, 0, stream>>>(
        x_h, qkvw_h, qkv_b, q_h, k_h, vt_h, nullptr, QKV_COLS / 128);

    // 2. Fused own+enc attention (round-5 chassis) -> xout_h + loss
    attn_fused<<<16 * BH, 256, 0, stream>>>(
        q_h, k_h, vt_h, ek_h, evt_h, xout_h, out + OUT_ELEMS);

    // 3. Output projection (64x128 tiles, grid 576: tail smoothing)
    gemm_mfma<1, 64><<<(PC / 128) * ((PB * PN) / 64), 128, 0, stream>>>(
        xout_h, projw_h, proj_b, nullptr, nullptr, nullptr, out, PC / 128);
}